// Round 5
// baseline (673.919 us; speedup 1.0000x reference)
//
#include <hip/hip_runtime.h>
#include <hip/hip_bf16.h>

// DecomposableAttentionEncoder, MI355X bf16-MFMA implementation.
// B=32, M=N=512, S=H=512, MAXD=11. Masks are all-True => ignored.
// R2..R16: see history. 648 us baseline.
// R17: gemm256_kernel (256x256/BK=64, 4-phase counted-vmcnt, LDS XOR
// swizzle, setprio). MLP/cmp GEMMs won (cmp1 100->76), batched shapes lost.
// R18: regime routing (gemm256 only for M=32768 GEMMs). 645.
// R19: attn_kernel fused score+bias+softmax. 682 - 6x B-panel over-fetch
// (8 q-blocks of a batch round-robin onto 8 different XCDs).
// R20: XCD-affine batch mapping in attn. 622. attn ~48us each; top = cmp1
// 76us (904 TF). Remaining fat: PV GEMMs (batched M=512 K=512 slow regime,
// ~130-150us combined) + 67MB att round-trip that only carries P.
// R21: attnpv_kernel - full fusion score+softmax+PV. 8 waves/block:
// score phase keys split 8-ways; P (bf16 64x520-pad, 66.6KB) overlays the
// dead score dbuf in LDS; PV phase d split 8-ways, V double-buffered
// (2x33.8KB) from premcat (L2-hot, XCD-affine), mfma A=P (b128 reads,
// pitch-padded) B=V (scalar u16 NB reads, R14-neutral). Kills both PV
// dispatches + att buffer traffic. 1 block/CU but same 8 waves/CU.

typedef __bf16 bf16x8 __attribute__((ext_vector_type(8)));
typedef float floatx16 __attribute__((ext_vector_type(16)));
typedef float floatx4 __attribute__((ext_vector_type(4)));

__device__ __forceinline__ unsigned short f32_to_bf16(float f) {
    unsigned int u = __float_as_uint(f);
    unsigned int r = (u + 0x7FFFu + ((u >> 16) & 1u)) >> 16;
    return (unsigned short)r;
}
__device__ __forceinline__ float bf16_to_f32(unsigned short h) {
    return __uint_as_float(((unsigned int)h) << 16);
}

// async global->LDS, 16B per lane (wave-uniform base + lane*16, m104).
__device__ __forceinline__ void gload16(const void* g, void* l) {
    __builtin_amdgcn_global_load_lds(
        (const __attribute__((address_space(1))) unsigned int*)g,
        (__attribute__((address_space(3))) unsigned int*)l, 16, 0, 0);
}

#define FENCE_BAR() do { asm volatile("" ::: "memory"); \
    __builtin_amdgcn_s_barrier(); \
    asm volatile("" ::: "memory"); } while (0)

// ------------------------------------------- all weight transposes, one dispatch
struct TW {
    const float* src[8];
    unsigned short* dst[8];
    int K[8];
};
__global__ __launch_bounds__(256) void transpose_all_kernel(TW tw) {
    const int z = blockIdx.z;
    const int K = tw.K[z];
    const int k0 = blockIdx.y * 32;
    if (k0 >= K) return;
    const float* W = tw.src[z];
    unsigned short* Wt = tw.dst[z];
    __shared__ unsigned short tile[32][33];
    int n0 = blockIdx.x * 32;
    int tx = threadIdx.x & 31, ty = threadIdx.x >> 5;  // 32 x 8
    #pragma unroll
    for (int i = 0; i < 4; ++i) {
        int ky = ty + i * 8;
        tile[ky][tx] = f32_to_bf16(W[(long long)(k0 + ky) * 512 + n0 + tx]);
    }
    __syncthreads();
    #pragma unroll
    for (int i = 0; i < 4; ++i) {
        int ny = ty + i * 8;
        Wt[(long long)(n0 + ny) * K + k0 + tx] = tile[tx][ny];
    }
}

// ---------------------------------------------------------------- MFMA GEMM
// (old 128x128 2-barrier kernel - 4 blocks/CU; AF32 / csum paths)
template <bool BT, bool AF32>
__global__ __launch_bounds__(256, 4) void gemm_kernel(
    const void* __restrict__ Av, const void* __restrict__ A2v, int lda, long long strideA,
    const unsigned short* __restrict__ Bw, int ldb, long long strideB, int bxor,
    const unsigned short* __restrict__ B2, const float* __restrict__ bias2, int Msplit,
    float* __restrict__ C32, unsigned short* __restrict__ Cb, int ldc, long long strideC,
    const float* __restrict__ bias, int relu, int M, int N, int K,
    float* __restrict__ csum, int swz) {
    constexpr int BBYTES = BT ? 8192 : (32 * 264);  // NB: 8448
    constexpr int BUF = 8192 + BBYTES;
    __shared__ alignas(16) char smem[2 * BUF];

    const int t = threadIdx.x;
    const int lane = t & 63;
    const int wave = t >> 6;
    const int wm = (wave >> 1) * 64;
    const int wn = (wave & 1) * 64;
    const int ln = lane & 31;   // m/n within 32-subtile
    const int h = lane >> 5;    // k-half

    int bx = blockIdx.x, by = blockIdx.y, bz = blockIdx.z;
    if (swz == 1) {             // batch-1: same-A groups per XCD
        int Nt = gridDim.x, Mt = gridDim.y;
        int L = by * Nt + bx;
        int x = L & 7, s = L >> 3;
        by = x * (Mt >> 3) + s / Nt;
        bx = s % Nt;
    } else if (swz == 2) {      // batched: same-(bz,by) n-blocks per XCD
        int Nt = gridDim.x, Mt = gridDim.y;
        int L = (bz * Mt + by) * Nt + bx;
        int x = L & 7, s = L >> 3;
        int mg = x * ((Mt * (int)gridDim.z) >> 3) + s / Nt;
        bx = s % Nt;
        by = mg % Mt;
        bz = mg / Mt;
    }
    const int m0 = by * 128;
    const int n0 = bx * 128;
    const int bzB = (bz + bxor) & ((int)gridDim.z - 1);

    // per-row operand switch (merged projection)
    const unsigned short* B = Bw;
    const float* biasp = bias;
    long long mA = m0;
    if (Msplit && m0 >= Msplit) {
        if (B2) B = B2;
        if (bias2) biasp = bias2;
        if (A2v) { Av = A2v; mA = m0 - Msplit; }
    }

    const float* aptrF = nullptr;
    const unsigned short* aptrH = nullptr;
    if constexpr (AF32)
        aptrF = (const float*)Av + (long long)bz * strideA +
                (mA + (t >> 1)) * (long long)lda + (t & 1) * 16;
    else
        aptrH = (const unsigned short*)Av + (long long)bz * strideA +
                (mA + (t >> 1)) * (long long)lda + (t & 1) * 16;
    const unsigned short* bptr;
    if (BT)
        bptr = B + (long long)bzB * strideB +
               (long long)(n0 + (t >> 1)) * ldb + (t & 1) * 16;
    else
        bptr = B + (long long)bzB * strideB +
               (long long)(t >> 4) * ldb + n0 + (t & 15) * 8;
    const long long bstep = BT ? 8 : 16 * (long long)ldb;

    const int aoff = ((t & 1) * 256 + (t >> 1)) * 16;
    const int boff = BT ? (8192 + ((t & 1) * 256 + (t >> 1)) * 16)
                        : (8192 + (t >> 4) * 264 + (t & 15) * 16);
    const int boff2 = BT ? 2048 : 16 * 264;

    floatx16 acc[2][2];
    #pragma unroll
    for (int im = 0; im < 2; ++im)
        #pragma unroll
        for (int in = 0; in < 2; ++in)
            acc[im][in] = (floatx16)(0.f);

    uint4 va0, va1, vb0, vb1;
    float4 fa0, fa1, fa2, fa3;

    auto loadA = [&]() {
        if constexpr (AF32) {
            fa0 = *(const float4*)(aptrF);
            fa1 = *(const float4*)(aptrF + 4);
            fa2 = *(const float4*)(aptrF + 8);
            fa3 = *(const float4*)(aptrF + 12);
            aptrF += 32;
        } else {
            va0 = *(const uint4*)(aptrH);
            va1 = *(const uint4*)(aptrH + 8);
            aptrH += 32;
        }
    };
    auto loadB = [&]() {
        vb0 = *(const uint4*)(bptr);
        vb1 = *(const uint4*)(bptr + bstep);
        bptr += BT ? 32 : 32 * (long long)ldb;
    };
    auto commit = [&](char* buf) {
        if constexpr (AF32) {
            union { uint4 q; unsigned short u[8]; } c0, c1;
            c0.u[0] = f32_to_bf16(fa0.x); c0.u[1] = f32_to_bf16(fa0.y);
            c0.u[2] = f32_to_bf16(fa0.z); c0.u[3] = f32_to_bf16(fa0.w);
            c0.u[4] = f32_to_bf16(fa1.x); c0.u[5] = f32_to_bf16(fa1.y);
            c0.u[6] = f32_to_bf16(fa1.z); c0.u[7] = f32_to_bf16(fa1.w);
            c1.u[0] = f32_to_bf16(fa2.x); c1.u[1] = f32_to_bf16(fa2.y);
            c1.u[2] = f32_to_bf16(fa2.z); c1.u[3] = f32_to_bf16(fa2.w);
            c1.u[4] = f32_to_bf16(fa3.x); c1.u[5] = f32_to_bf16(fa3.y);
            c1.u[6] = f32_to_bf16(fa3.z); c1.u[7] = f32_to_bf16(fa3.w);
            *(uint4*)(buf + aoff) = c0.q;
            *(uint4*)(buf + aoff + 2048) = c1.q;
        } else {
            *(uint4*)(buf + aoff) = va0;
            *(uint4*)(buf + aoff + 2048) = va1;
        }
        *(uint4*)(buf + boff) = vb0;
        *(uint4*)(buf + boff + boff2) = vb1;
    };

    loadA(); loadB();
    commit(smem);
    loadA(); loadB();
    __syncthreads();

    int p = 0;
    for (int k0 = 0; k0 < K; k0 += 32) {
        const char* base = smem + p * BUF;
        #pragma unroll
        for (int s = 0; s < 2; ++s) {
            bf16x8 a[2], b[2];
            #pragma unroll
            for (int im = 0; im < 2; ++im)
                a[im] = *(const bf16x8*)(base + ((s * 2 + h) * 128 + wm + im * 32 + ln) * 16);
            if (BT) {
                #pragma unroll
                for (int in = 0; in < 2; ++in)
                    b[in] = *(const bf16x8*)(base + 8192 +
                                             ((s * 2 + h) * 128 + wn + in * 32 + ln) * 16);
            } else {
                #pragma unroll
                for (int in = 0; in < 2; ++in) {
                    union { bf16x8 v; unsigned short u[8]; } u;
                    #pragma unroll
                    for (int j = 0; j < 8; ++j)
                        u.u[j] = *(const unsigned short*)(base + 8192 +
                                 (s * 16 + h * 8 + j) * 264 + (wn + in * 32 + ln) * 2);
                    b[in] = u.v;
                }
            }
            #pragma unroll
            for (int im = 0; im < 2; ++im)
                #pragma unroll
                for (int in = 0; in < 2; ++in)
                    acc[im][in] = __builtin_amdgcn_mfma_f32_32x32x16_bf16(
                        a[im], b[in], acc[im][in], 0, 0, 0);
        }

        if (k0 + 32 < K) {
            commit(smem + (p ^ 1) * BUF);
            if (k0 + 64 < K) { loadA(); loadB(); }
            __syncthreads();
            p ^= 1;
        }
    }

    if (csum) {
        const int bidx = m0 >> 9;
        const long long cbase = (long long)(bidx & 31) * 1024 + (bidx >> 5) * 512;
        #pragma unroll
        for (int in = 0; in < 2; ++in) {
            int n = n0 + wn + in * 32 + ln;
            float bn = biasp ? biasp[n] : 0.f;
            float s = 0.f;
            #pragma unroll
            for (int im = 0; im < 2; ++im)
                #pragma unroll
                for (int r = 0; r < 16; ++r) {
                    float v = acc[im][in][r] + bn;
                    if (relu) v = fmaxf(v, 0.f);
                    s += v;
                }
            s += __shfl_xor(s, 32);
            if (lane < 32) atomicAdd(&csum[cbase + n], s);
        }
        return;
    }

    float* C32b = C32 ? C32 + (long long)bz * strideC : nullptr;
    unsigned short* Cbb = Cb ? Cb + (long long)bz * strideC : nullptr;
    #pragma unroll
    for (int im = 0; im < 2; ++im) {
        #pragma unroll
        for (int in = 0; in < 2; ++in) {
            int n = n0 + wn + in * 32 + ln;
            float bn = biasp ? biasp[n] : 0.f;
            #pragma unroll
            for (int r = 0; r < 16; ++r) {
                int m = m0 + wm + im * 32 + (r & 3) + 8 * (r >> 2) + 4 * h;
                float v = acc[im][in][r] + bn;
                if (relu) v = fmaxf(v, 0.f);
                long long off = (long long)m * ldc + n;
                if (C32b) C32b[off] = v;
                if (Cbb) Cbb[off] = f32_to_bf16(v);
            }
        }
    }
}

// --------------------------------------------------- 256x256 8-phase GEMM
// (see R17 header comment; used for the five M=32768 weight GEMMs)
__global__ __launch_bounds__(512, 2) void gemm256_kernel(
    const unsigned short* __restrict__ Aw, int lda, long long strideA,
    const unsigned short* __restrict__ Bw, int ldb, long long strideB, int bxor,
    float* __restrict__ C32, unsigned short* __restrict__ Cb, int ldc, long long strideC,
    const float* __restrict__ bias, int relu, int K) {
    extern __shared__ __align__(16) char smem[];

    const int tid = threadIdx.x;
    const int lane = tid & 63;
    const int wave = tid >> 6;
    const int wr = wave >> 2;           // 0..1 -> 128-row half
    const int wc = wave & 3;            // 0..3 -> 64-col quarter

    int bx = blockIdx.x, by = blockIdx.y, bz = blockIdx.z;
    {
        const int gx = gridDim.x, gy = gridDim.y;
        const int nwg = gx * gy * (int)gridDim.z;
        if ((nwg & 7) == 0) {
            int L = (bz * gy + by) * gx + bx;
            int flat = (L & 7) * (nwg >> 3) + (L >> 3);
            bx = flat % gx;
            int R = flat / gx;
            by = R % gy;
            bz = R / gy;
        }
    }
    const int m0 = by * 256;
    const int n0 = bx * 256;
    const int bzB = (bz + bxor) & ((int)gridDim.z - 1);

    const int rowT = tid >> 3;                       // 0..63
    const int chS = (tid & 7) ^ (rowT & 7);
    const long long ldaB = (long long)lda * 2;
    const long long ldbB = (long long)ldb * 2;
    const char* aG = (const char*)Aw +
        ((long long)bz * strideA + (long long)(m0 + rowT) * lda) * 2 + chS * 16;
    const char* bG = (const char*)Bw +
        ((long long)bzB * strideB + (long long)(n0 + rowT) * ldb) * 2 + chS * 16;
    const int dOff = tid * 16;

    auto stA = [&](int tt, int h) {                  // stage A half-tile h of K-tile tt
        const char* g = aG + (long long)(h * 128) * ldaB + (long long)tt * 128;
        char* l = smem + (tt & 1) * 65536 + h * 16384 + dOff;
        gload16(g, l);
        gload16(g + 64 * ldaB, l + 8192);
    };
    auto stB = [&](int tt, int h) {
        const char* g = bG + (long long)(h * 128) * ldbB + (long long)tt * 128;
        char* l = smem + (tt & 1) * 65536 + 32768 + h * 16384 + dOff;
        gload16(g, l);
        gload16(g + 64 * ldbB, l + 8192);
    };

    const int l15 = lane & 15;
    const int lk = lane >> 4;                        // k-group 0..3
    const int swzb = (lane & 7) << 4;
    const int c0 = (lk * 16) ^ swzb;                 // kk=0 col bytes
    const int c1 = (64 + lk * 16) ^ swzb;            // kk=1
    const int arow = (wr * 128 + l15) * 128;
    const int brow = 32768 + (wc * 64 + l15) * 128;

    floatx4 acc[8][4];
    #pragma unroll
    for (int mf = 0; mf < 8; ++mf)
        #pragma unroll
        for (int nf = 0; nf < 4; ++nf)
            acc[mf][nf] = (floatx4)(0.f);

    const int NT = K >> 6;

    stA(0, 0); stA(0, 1); stB(0, 0); stB(0, 1);
    if (NT > 1) {
        stB(1, 0); stB(1, 1);
        asm volatile("s_waitcnt vmcnt(4)" ::: "memory");
    } else {
        asm volatile("s_waitcnt vmcnt(0)" ::: "memory");
    }
    FENCE_BAR();

    bf16x8 a[4][2], b[4][2];
    for (int t = 0; t < NT; ++t) {
        const char* buf = smem + (t & 1) * 65536;
        const char* aB = buf + arow;
        const char* bB = buf + brow;

        // ---- P0: A mf0-3 + B nf0-1; stage A(t+1) h0
        #pragma unroll
        for (int mf = 0; mf < 4; ++mf) {
            a[mf][0] = *(const bf16x8*)(aB + mf * 2048 + c0);
            a[mf][1] = *(const bf16x8*)(aB + mf * 2048 + c1);
        }
        #pragma unroll
        for (int nf = 0; nf < 2; ++nf) {
            b[nf][0] = *(const bf16x8*)(bB + nf * 2048 + c0);
            b[nf][1] = *(const bf16x8*)(bB + nf * 2048 + c1);
        }
        if (t + 1 < NT) stA(t + 1, 0);
        FENCE_BAR();
        __builtin_amdgcn_s_setprio(1);
        #pragma unroll
        for (int mf = 0; mf < 4; ++mf)
            #pragma unroll
            for (int nf = 0; nf < 2; ++nf) {
                acc[mf][nf] = __builtin_amdgcn_mfma_f32_16x16x32_bf16(
                    a[mf][0], b[nf][0], acc[mf][nf], 0, 0, 0);
                acc[mf][nf] = __builtin_amdgcn_mfma_f32_16x16x32_bf16(
                    a[mf][1], b[nf][1], acc[mf][nf], 0, 0, 0);
            }
        __builtin_amdgcn_s_setprio(0);
        FENCE_BAR();

        // ---- P1: B nf2-3; stage A(t+1) h1
        #pragma unroll
        for (int nf = 2; nf < 4; ++nf) {
            b[nf][0] = *(const bf16x8*)(bB + nf * 2048 + c0);
            b[nf][1] = *(const bf16x8*)(bB + nf * 2048 + c1);
        }
        if (t + 1 < NT) stA(t + 1, 1);
        FENCE_BAR();
        __builtin_amdgcn_s_setprio(1);
        #pragma unroll
        for (int mf = 0; mf < 4; ++mf)
            #pragma unroll
            for (int nf = 2; nf < 4; ++nf) {
                acc[mf][nf] = __builtin_amdgcn_mfma_f32_16x16x32_bf16(
                    a[mf][0], b[nf][0], acc[mf][nf], 0, 0, 0);
                acc[mf][nf] = __builtin_amdgcn_mfma_f32_16x16x32_bf16(
                    a[mf][1], b[nf][1], acc[mf][nf], 0, 0, 0);
            }
        __builtin_amdgcn_s_setprio(0);
        FENCE_BAR();

        // ---- P2: A mf4-7; stage B(t+2) h0
        #pragma unroll
        for (int mf = 0; mf < 4; ++mf) {
            a[mf][0] = *(const bf16x8*)(aB + (4 + mf) * 2048 + c0);
            a[mf][1] = *(const bf16x8*)(aB + (4 + mf) * 2048 + c1);
        }
        if (t + 2 < NT) stB(t + 2, 0);
        FENCE_BAR();
        __builtin_amdgcn_s_setprio(1);
        #pragma unroll
        for (int mf = 0; mf < 4; ++mf)
            #pragma unroll
            for (int nf = 2; nf < 4; ++nf) {
                acc[4 + mf][nf] = __builtin_amdgcn_mfma_f32_16x16x32_bf16(
                    a[mf][0], b[nf][0], acc[4 + mf][nf], 0, 0, 0);
                acc[4 + mf][nf] = __builtin_amdgcn_mfma_f32_16x16x32_bf16(
                    a[mf][1], b[nf][1], acc[4 + mf][nf], 0, 0, 0);
            }
        __builtin_amdgcn_s_setprio(0);
        FENCE_BAR();

        // ---- P3: stage B(t+2) h1; counted vmcnt => tile t+1 landed
        if (t + 2 < NT) {
            stB(t + 2, 1);
            asm volatile("s_waitcnt vmcnt(4)" ::: "memory");
        } else {
            asm volatile("s_waitcnt vmcnt(0)" ::: "memory");
        }
        FENCE_BAR();
        __builtin_amdgcn_s_setprio(1);
        #pragma unroll
        for (int mf = 0; mf < 4; ++mf)
            #pragma unroll
            for (int nf = 0; nf < 2; ++nf) {
                acc[4 + mf][nf] = __builtin_amdgcn_mfma_f32_16x16x32_bf16(
                    a[mf][0], b[nf][0], acc[4 + mf][nf], 0, 0, 0);
                acc[4 + mf][nf] = __builtin_amdgcn_mfma_f32_16x16x32_bf16(
                    a[mf][1], b[nf][1], acc[4 + mf][nf], 0, 0, 0);
            }
        __builtin_amdgcn_s_setprio(0);
        FENCE_BAR();
    }

    // ---- epilogue: C/D map col=lane&15, row=(lane>>4)*4+r (m89)
    const int rg = (lane >> 4) * 4;
    float* C32b = C32 ? C32 + (long long)bz * strideC : nullptr;
    unsigned short* Cbb = Cb ? Cb + (long long)bz * strideC : nullptr;
    #pragma unroll
    for (int nf = 0; nf < 4; ++nf) {
        const int n = n0 + wc * 64 + nf * 16 + l15;
        const float bn = bias ? bias[n] : 0.f;
        #pragma unroll
        for (int mf = 0; mf < 8; ++mf) {
            #pragma unroll
            for (int r = 0; r < 4; ++r) {
                int m = m0 + wr * 128 + mf * 16 + rg + r;
                float v = acc[mf][nf][r] + bn;
                if (relu) v = fmaxf(v, 0.f);
                long long off = (long long)m * ldc + n;
                if (C32b) C32b[off] = v;
                if (Cbb) Cbb[off] = f32_to_bf16(v);
            }
        }
    }
}

// ------------------- fused score + rel-bias + softmax + PV (attention)
// One block: 64 q rows x all 512 keys x 1 batch. 512 threads = 8 waves.
// Score phase: waves = key-eighths (64 keys each), acc[2 m][2 n] of 32x32.
// Softmax in-register: in-lane max/sum -> shfl_xor(16..1) -> [64][8] LDS
// cross-wave round. P (bf16 [64 q][520-pad k], 66.6KB) written into LDS
// (overlays the dead score dbuf). PV phase: waves = d-eighths (self 64 /
// cross 128 cols), V = premcat[bzB][keys][0:D] double-buffered in LDS,
// A=P b128 reads (pitch 1040B -> 4-way conflict, ok), B=V scalar u16 NB
// reads (R14-neutral). ctx written directly into premcat cols [dst..dst+D).
// XCD-affine mapping (R20): 8 q-blocks of a batch on one XCD -> V L2-hot.
// LDS: max(score dbuf 73.7KB, P 66.6 + 2xV 67.6) = 134KB -> 1 block/CU,
// same 8 waves/CU as the R20 2-block config.
template <bool CROSS>
__global__ __launch_bounds__(512, 1) void attnpv_kernel(
    const unsigned short* __restrict__ F,    // [64][512][512] bf16 features
    const unsigned short* __restrict__ Vsrc, // premcat base [64][512][2048]
    int bxor,
    unsigned short* __restrict__ ctxout,     // premcat + dstoff, lda 2048
    const float* __restrict__ de, int rel) {
    constexpr int D   = CROSS ? 1024 : 512;   // V width
    constexpr int KS  = CROSS ? 16 : 32;      // keys per PV step
    constexpr int NS  = 512 / KS;             // PV steps
    constexpr int VP  = CROSS ? 2080 : 1056;  // V row pitch bytes (16B mult)
    constexpr int DS  = CROSS ? 4 : 2;        // d-subtiles per wave
    constexpr int WD  = CROSS ? 128 : 64;     // d-cols per wave
    constexpr int PBASE = 66560;              // P region [0,66560)
    constexpr int VBYTES = KS * VP;
    constexpr int SBUF = 36864;               // score buf: A 4KB + B 32KB

    extern __shared__ __align__(16) char smem[];
    __shared__ float red[2][64][8];
    __shared__ float deL[23];

    const int t = threadIdx.x;
    const int lane = t & 63;
    const int wave = t >> 6;                 // key-eighth / d-eighth
    const int ln = lane & 31;
    const int h = lane >> 5;

    // XCD-affine remap (R20)
    const int orig = blockIdx.y * (int)gridDim.x + blockIdx.x;
    const int xcd = orig & 7;
    const int s8 = orig >> 3;
    const int by = s8 & 7;
    const int bz = xcd + ((s8 >> 3) << 3);
    const int m0 = by * 64;
    const int bzB = (bz + bxor) & 63;

    if (t < 23) deL[t] = de[t];

    // ---- score staging: A (t<256): row t>>2, plane t&3; B: row t, 4 planes
    const unsigned short* aptr = F + (long long)bz * (512 * 512) +
                                 (m0 + (t >> 2)) * 512 + (t & 3) * 8;
    const unsigned short* bptr = F + (long long)bzB * (512 * 512) + t * 512;
    const int aoff = ((t & 3) * 64 + (t >> 2)) * 16;
    const int boffB = t * 16;

    floatx16 acc[2][2];
    #pragma unroll
    for (int mf = 0; mf < 2; ++mf)
        #pragma unroll
        for (int nf = 0; nf < 2; ++nf)
            acc[mf][nf] = (floatx16)(0.f);

    uint4 qa, qb0, qb1, qb2, qb3;
    auto load = [&]() {
        if (t < 256) qa = *(const uint4*)(aptr);
        qb0 = *(const uint4*)(bptr);
        qb1 = *(const uint4*)(bptr + 8);
        qb2 = *(const uint4*)(bptr + 16);
        qb3 = *(const uint4*)(bptr + 24);
        aptr += 32; bptr += 32;
    };
    auto commit = [&](char* buf) {
        if (t < 256) *(uint4*)(buf + aoff) = qa;
        char* bb = buf + 4096;
        *(uint4*)(bb + 0 * 8192 + boffB) = qb0;
        *(uint4*)(bb + 1 * 8192 + boffB) = qb1;
        *(uint4*)(bb + 2 * 8192 + boffB) = qb2;
        *(uint4*)(bb + 3 * 8192 + boffB) = qb3;
    };

    load(); commit(smem); load();
    __syncthreads();

    int p = 0;
    for (int k0 = 0; k0 < 512; k0 += 32) {
        const char* buf = smem + p * SBUF;
        #pragma unroll
        for (int s = 0; s < 2; ++s) {
            bf16x8 a[2], b[2];
            #pragma unroll
            for (int mf = 0; mf < 2; ++mf)
                a[mf] = *(const bf16x8*)(buf + ((s * 2 + h) * 64 + mf * 32 + ln) * 16);
            #pragma unroll
            for (int nf = 0; nf < 2; ++nf)
                b[nf] = *(const bf16x8*)(buf + 4096 + (s * 2 + h) * 8192 +
                                         (wave * 64 + nf * 32 + ln) * 16);
            #pragma unroll
            for (int mf = 0; mf < 2; ++mf)
                #pragma unroll
                for (int nf = 0; nf < 2; ++nf)
                    acc[mf][nf] = __builtin_amdgcn_mfma_f32_32x32x16_bf16(
                        a[mf], b[nf], acc[mf][nf], 0, 0, 0);
        }
        if (k0 + 32 < 512) {
            commit(smem + (p ^ 1) * SBUF);
            if (k0 + 64 < 512) load();
            __syncthreads();
            p ^= 1;
        }
    }

    // ---- rel-distance bias (self-attention only)
    if (rel) {
        #pragma unroll
        for (int mf = 0; mf < 2; ++mf)
            #pragma unroll
            for (int nf = 0; nf < 2; ++nf)
                #pragma unroll
                for (int r = 0; r < 16; ++r) {
                    int row = m0 + mf * 32 + (r & 3) + 8 * (r >> 2) + 4 * h;
                    int col = wave * 64 + nf * 32 + ln;
                    int d = min(11, max(-11, col - row));
                    acc[mf][nf][r] += deL[d + 11];
                }
    }

    // ---- row max
    #pragma unroll
    for (int mf = 0; mf < 2; ++mf)
        #pragma unroll
        for (int r = 0; r < 16; ++r) {
            float mx = fmaxf(acc[mf][0][r], acc[mf][1][r]);
            #pragma unroll
            for (int o = 16; o > 0; o >>= 1) mx = fmaxf(mx, __shfl_xor(mx, o));
            if (ln == 0)
                red[0][mf * 32 + (r & 3) + 8 * (r >> 2) + 4 * h][wave] = mx;
        }
    __syncthreads();

    // ---- exp + row sum
    #pragma unroll
    for (int mf = 0; mf < 2; ++mf)
        #pragma unroll
        for (int r = 0; r < 16; ++r) {
            const int rl = mf * 32 + (r & 3) + 8 * (r >> 2) + 4 * h;
            float4 qm0 = *(const float4*)&red[0][rl][0];
            float4 qm1 = *(const float4*)&red[0][rl][4];
            float mx = fmaxf(fmaxf(fmaxf(qm0.x, qm0.y), fmaxf(qm0.z, qm0.w)),
                             fmaxf(fmaxf(qm1.x, qm1.y), fmaxf(qm1.z, qm1.w)));
            float s = 0.f;
            #pragma unroll
            for (int nf = 0; nf < 2; ++nf) {
                acc[mf][nf][r] = __expf(acc[mf][nf][r] - mx);
                s += acc[mf][nf][r];
            }
            #pragma unroll
            for (int o = 16; o > 0; o >>= 1) s += __shfl_xor(s, o);
            if (ln == 0) red[1][rl][wave] = s;
        }
    __syncthreads();   // also: all score-dbuf reads complete before P overlay

    // ---- PV staging pointers (issue V(0) loads before P write to overlap)
    const unsigned short* vG = Vsrc + (long long)bzB * (512 * 2048);
    const int vrow = CROSS ? (t >> 5) : (t >> 4);
    const int vch = (CROSS ? (t & 31) : (t & 15)) * 4;   // 16B chunks
    const unsigned short* vptr = vG + (long long)vrow * 2048 + vch * 8;
    uint4 v0, v1, v2, v3;
    auto vload = [&](int s) {
        const unsigned short* g = vptr + (long long)s * KS * 2048;
        v0 = *(const uint4*)(g);
        v1 = *(const uint4*)(g + 8);
        v2 = *(const uint4*)(g + 16);
        v3 = *(const uint4*)(g + 24);
    };
    auto vcommit = [&](int vb) {
        char* b = smem + PBASE + vb * VBYTES + vrow * VP + vch * 16;
        *(uint4*)(b) = v0;
        *(uint4*)(b + 16) = v1;
        *(uint4*)(b + 32) = v2;
        *(uint4*)(b + 48) = v3;
    };

    vload(0);   // in flight while we normalize + write P

    // ---- normalize + write P bf16 to LDS [64 q][pitch 1040B]
    #pragma unroll
    for (int mf = 0; mf < 2; ++mf)
        #pragma unroll
        for (int r = 0; r < 16; ++r) {
            const int rl = mf * 32 + (r & 3) + 8 * (r >> 2) + 4 * h;
            float4 qs0 = *(const float4*)&red[1][rl][0];
            float4 qs1 = *(const float4*)&red[1][rl][4];
            float inv = 1.f / (qs0.x + qs0.y + qs0.z + qs0.w +
                               qs1.x + qs1.y + qs1.z + qs1.w);
            #pragma unroll
            for (int nf = 0; nf < 2; ++nf) {
                int key = wave * 64 + nf * 32 + ln;
                *(unsigned short*)(smem + rl * 1040 + key * 2) =
                    f32_to_bf16(acc[mf][nf][r] * inv);
            }
        }
    __syncthreads();   // P visible; score dbuf fully dead

    vcommit(0);
    if (NS > 1) vload(1);
    __syncthreads();   // V(0) visible

    // ---- PV: out[64 q][D], wave owns d-slice [wave*WD, +WD)
    floatx16 pacc[2][DS];
    #pragma unroll
    for (int mf = 0; mf < 2; ++mf)
        #pragma unroll
        for (int df = 0; df < DS; ++df)
            pacc[mf][df] = (floatx16)(0.f);

    int vp = 0;
    for (int s = 0; s < NS; ++s) {
        const char* Vb = smem + PBASE + vp * VBYTES;
        const int kk0 = s * KS;
        #pragma unroll
        for (int ks = 0; ks < KS / 16; ++ks) {
            bf16x8 pa[2];
            #pragma unroll
            for (int mf = 0; mf < 2; ++mf)
                pa[mf] = *(const bf16x8*)(smem + (mf * 32 + ln) * 1040 +
                                          (kk0 + ks * 16 + h * 8) * 2);
            #pragma unroll
            for (int df = 0; df < DS; ++df) {
                union { bf16x8 v; unsigned short u[8]; } vb;
                #pragma unroll
                for (int j = 0; j < 8; ++j)
                    vb.u[j] = *(const unsigned short*)(Vb +
                              (ks * 16 + h * 8 + j) * VP +
                              (wave * WD + df * 32 + ln) * 2);
                #pragma unroll
                for (int mf = 0; mf < 2; ++mf)
                    pacc[mf][df] = __builtin_amdgcn_mfma_f32_32x32x16_bf16(
                        pa[mf], vb.v, pacc[mf][df], 0, 0, 0);
            }
        }
        if (s + 1 < NS) {
            vcommit(vp ^ 1);
            if (s + 2 < NS) vload(s + 2);
        }
        __syncthreads();
        vp ^= 1;
    }

    // ---- epilogue: ctx -> premcat cols (lda 2048)
    unsigned short* cb = ctxout + ((long long)bz * 512 + m0) * 2048;
    #pragma unroll
    for (int mf = 0; mf < 2; ++mf)
        #pragma unroll
        for (int r = 0; r < 16; ++r) {
            const int q = mf * 32 + (r & 3) + 8 * (r >> 2) + 4 * h;
            #pragma unroll
            for (int df = 0; df < DS; ++df) {
                int col = wave * WD + df * 32 + ln;
                cb[(long long)q * 2048 + col] = f32_to_bf16(pacc[mf][df][r]);
            }
        }
}

// ------------------------------------------- aggregate MLP layer (fp32)
__global__ __launch_bounds__(512) void mlp_agg_kernel(const float* __restrict__ X,
                                                      const float* __restrict__ W,
                                                      const float* __restrict__ bias,
                                                      float* __restrict__ out,
                                                      int K, int N, int relu) {
    const int b = blockIdx.y;
    const int nl = threadIdx.x & 63;
    const int n = blockIdx.x * 64 + nl;
    const int ks = threadIdx.x >> 6;          // 0..7
    const int kchunk = K >> 3;
    const float* Xb = X + (long long)b * K;
    const int k0 = ks * kchunk;
    float s = 0.f;
    #pragma unroll 8
    for (int k = k0; k < k0 + kchunk; ++k)
        s += Xb[k] * W[(long long)k * N + n];
    __shared__ float red[8][64];
    red[ks][nl] = s;
    __syncthreads();
    if (threadIdx.x < 64) {
        float t = 0.f;
        #pragma unroll
        for (int i = 0; i < 8; ++i) t += red[i][threadIdx.x];
        t += bias[n];
        if (relu) t = fmaxf(t, 0.f);
        out[(long long)b * N + n] = t;
    }
}

// ---------------------------------------------------------------- host side
static void gemm(hipStream_t st, bool bt, bool af32,
                 const void* A, const void* A2, int lda, long long sA,
                 const void* B, int ldb, long long sB, int bxor,
                 const void* B2, const float* bias2, int Msplit,
                 float* C32, void* Cb, int ldc, long long sC,
                 const float* bias, int relu, int M, int N, int K, int batch,
                 float* csum = nullptr) {
    dim3 g(N / 128, M / 128, batch), blk(256);
    int swz = 0;
    if (batch == 1 && (M / 128) % 8 == 0) swz = 1;
    else if (batch > 1 && ((M / 128) * batch) % 8 == 0) swz = 2;
    if (bt) {
        if (af32)
            gemm_kernel<true, true><<<g, blk, 0, st>>>(
                A, A2, lda, sA, (const unsigned short*)B, ldb, sB, bxor,
                (const unsigned short*)B2, bias2, Msplit,
                C32, (unsigned short*)Cb, ldc, sC, bias, relu, M, N, K, csum, swz);
        else
            gemm_kernel<true, false><<<g, blk, 0, st>>>(
                A, A2, lda, sA, (const unsigned short*)B, ldb, sB, bxor,
                (const unsigned short*)B2, bias2, Msplit,
                C32, (unsigned short*)Cb, ldc, sC, bias, relu, M, N, K, csum, swz);
    } else {
        gemm_kernel<false, false><<<g, blk, 0, st>>>(
            A, A2, lda, sA, (const unsigned short*)B, ldb, sB, bxor,
            (const unsigned short*)B2, bias2, Msplit,
            C32, (unsigned short*)Cb, ldc, sC, bias, relu, M, N, K, csum, swz);
    }
}

static void gemm256(hipStream_t st,
                    const void* A, int lda, long long sA,
                    const void* B, int ldb, long long sB, int bxor,
                    float* C32, void* Cb, int ldc, long long sC,
                    const float* bias, int relu, int M, int N, int K, int batch) {
    static bool inited = false;
    if (!inited) {
        hipFuncSetAttribute(reinterpret_cast<const void*>(gemm256_kernel),
                            hipFuncAttributeMaxDynamicSharedMemorySize, 131072);
        inited = true;
    }
    dim3 g(N / 256, M / 256, batch);
    gemm256_kernel<<<g, 512, 131072, st>>>(
        (const unsigned short*)A, lda, sA,
        (const unsigned short*)B, ldb, sB, bxor,
        C32, (unsigned short*)Cb, ldc, sC, bias, relu, K);
}

extern "C" void kernel_launch(void* const* d_in, const int* in_sizes, int n_in,
                              void* d_out, int out_size, void* d_ws, size_t ws_size,
                              hipStream_t stream) {
    const int B = 32, SEQ = 512;
    const int MT = B * SEQ;      // 16384 rows per side
    const int M2 = 2 * MT;       // 32768 merged rows

    const float* prem = (const float*)d_in[0];
    const float* hypo = (const float*)d_in[1];
    const float* Wpx = (const float*)d_in[4];  const float* bpx = (const float*)d_in[5];
    const float* Wpy = (const float*)d_in[6];  const float* bpy = (const float*)d_in[7];
    const float* de  = (const float*)d_in[8];
    const float* Ws1 = (const float*)d_in[9];  const float* bs1 = (const float*)d_in[10];
    const float* Ws2 = (const float*)d_in[11]; const float* bs2 = (const float*)d_in[12];
    const float* Wa1 = (const float*)d_in[13]; const float* ba1 = (const float*)d_in[14];
    const float* Wa2 = (const float*)d_in[15]; const float* ba2 = (const float*)d_in[16];
    const float* Wc1 = (const float*)d_in[17]; const float* bc1 = (const float*)d_in[18];
    const float* Wc2 = (const float*)d_in[19]; const float* bc2 = (const float*)d_in[20];
    const float* Wg1 = (const float*)d_in[21]; const float* bg1 = (const float*)d_in[22];
    const float* Wg2 = (const float*)d_in[23]; const float* bg2 = (const float*)d_in[24];

    // ---- workspace carve (bytes, 256-aligned). Adjacency REQUIRED:
    // prem_bf|hypo_bf contiguous, premcat|hypocat contiguous. h1 aliases
    // the 64MB scratch region (scores name kept for continuity).
    char* p = (char*)d_ws;
    auto alloc = [&](size_t bytes) { char* r = p; p += (bytes + 255) & ~(size_t)255; return r; };
    unsigned short* prem_bf = (unsigned short*)alloc((size_t)MT * 512 * 2);
    unsigned short* hypo_bf = (unsigned short*)alloc((size_t)MT * 512 * 2);
    unsigned short* premcat = (unsigned short*)alloc((size_t)MT * 2048 * 2);
    unsigned short* hypocat = (unsigned short*)alloc((size_t)MT * 2048 * 2);
    float* scores = (float*)alloc((size_t)64 * SEQ * SEQ * 4);                  // 64 MB
    unsigned short* h1 = (unsigned short*)scores;                               // alias
    unsigned short* Wpx_t = (unsigned short*)alloc(512 * 512 * 2);
    unsigned short* Wpy_t = (unsigned short*)alloc(512 * 512 * 2);
    unsigned short* Ws1_t = (unsigned short*)alloc(512 * 512 * 2);
    unsigned short* Ws2_t = (unsigned short*)alloc(512 * 512 * 2);
    unsigned short* Wa1_t = (unsigned short*)alloc(512 * 1024 * 2);
    unsigned short* Wa2_t = (unsigned short*)alloc(512 * 512 * 2);
    unsigned short* Wc1_t = (unsigned short*)alloc(512 * 2048 * 2);
    unsigned short* Wc2_t = (unsigned short*)alloc(512 * 512 * 2);
    float* agg  = (float*)alloc(32 * 1024 * 4);
    float* aggh = (float*)alloc(32 * 512 * 4);
    (void)hypo_bf; (void)hypocat; (void)scores;

    const long long sCat = (long long)SEQ * 2048;     // cat batch stride

    // ---- setup: all 8 weight transposes in ONE dispatch; zero agg;
    // set dynamic-LDS caps for the big kernels (host-side, graph-safe)
    {
        static bool inited = false;
        if (!inited) {
            hipFuncSetAttribute(reinterpret_cast<const void*>(attnpv_kernel<false>),
                                hipFuncAttributeMaxDynamicSharedMemorySize, 134144);
            hipFuncSetAttribute(reinterpret_cast<const void*>(attnpv_kernel<true>),
                                hipFuncAttributeMaxDynamicSharedMemorySize, 134144);
            inited = true;
        }
        TW tw;
        tw.src[0] = Wpy; tw.dst[0] = Wpy_t; tw.K[0] = 512;
        tw.src[1] = Wpx; tw.dst[1] = Wpx_t; tw.K[1] = 512;
        tw.src[2] = Ws1; tw.dst[2] = Ws1_t; tw.K[2] = 512;
        tw.src[3] = Ws2; tw.dst[3] = Ws2_t; tw.K[3] = 512;
        tw.src[4] = Wa1; tw.dst[4] = Wa1_t; tw.K[4] = 1024;
        tw.src[5] = Wa2; tw.dst[5] = Wa2_t; tw.K[5] = 512;
        tw.src[6] = Wc1; tw.dst[6] = Wc1_t; tw.K[6] = 2048;
        tw.src[7] = Wc2; tw.dst[7] = Wc2_t; tw.K[7] = 512;
        transpose_all_kernel<<<dim3(16, 64, 8), 256, 0, stream>>>(tw);
        hipMemsetAsync(agg, 0, 32 * 1024 * sizeof(float), stream);
    }

    // ---- merged projection (fp32 A, per-row switch) - old kernel
    gemm(stream, true, true, prem, hypo, 512, 0, Wpy_t, 512, 0, 0,
         Wpx_t, bpx, MT, nullptr, premcat, 2048, 0, bpy, 0, M2, 512, 512, 1);

    // ---- self-attention MLP, merged: f = mlp2(cat[:, :512])  [gemm256]
    gemm256(stream, premcat, 2048, 0, Ws1_t, 512, 0, 0,
            nullptr, h1, 512, 0, bs1, 1, M2, 512, 512, 1);
    gemm256(stream, h1, 512, 0, Ws2_t, 512, 0, 0,
            nullptr, prem_bf, 512, 0, bs2, 1, M2, 512, 512, 1);

    // ---- self attention: fused score+bias+softmax+PV -> premcat[:,512:1024]
    attnpv_kernel<false><<<dim3(8, 64), 512, 134144, stream>>>(
        prem_bf, premcat, 0, premcat + 512, de, 1);

    // ---- cross-attention MLP, merged: g = mlp2(cat[:, :1024])  [gemm256]
    gemm256(stream, premcat, 2048, 0, Wa1_t, 1024, 0, 0,
            nullptr, h1, 512, 0, ba1, 1, M2, 512, 1024, 1);
    gemm256(stream, h1, 512, 0, Wa2_t, 512, 0, 0,
            nullptr, prem_bf, 512, 0, ba2, 1, M2, 512, 512, 1);

    // ---- cross attention: fused, B-batch rotation (z+32)&63,
    //      V = premcat[:, :1024] of other side -> premcat[:,1024:2048]
    attnpv_kernel<true><<<dim3(8, 64), 512, 134144, stream>>>(
        prem_bf, premcat, 32, premcat + 1024, de, 0);

    // ---- compare, merged: cmp = mlp2(cat) ; fused column-sum into agg
    gemm256(stream, premcat, 2048, 0, Wc1_t, 2048, 0, 0,
            nullptr, h1, 512, 0, bc1, 1, M2, 512, 2048, 1);
    gemm(stream, true, false, h1, nullptr, 512, 0, Wc2_t, 512, 0, 0,
         nullptr, nullptr, 0, nullptr, nullptr, 512, 0, bc2, 1, M2, 512, 512, 1, agg);

    // ---- aggregate MLP
    mlp_agg_kernel<<<dim3(8, 32), 512, 0, stream>>>(agg, Wg1, bg1, aggh, 1024, 512, 1);
    mlp_agg_kernel<<<dim3(8, 32), 512, 0, stream>>>(aggh, Wg2, bg2, (float*)d_out, 512, 512, 1);
}

// Round 6
// 619.621 us; speedup vs baseline: 1.0876x; 1.0876x over previous
//
#include <hip/hip_runtime.h>
#include <hip/hip_bf16.h>

// DecomposableAttentionEncoder, MI355X bf16-MFMA implementation.
// B=32, M=N=512, S=H=512, MAXD=11. Masks are all-True => ignored.
// R2..R16: see history. 648 us baseline.
// R17: gemm256_kernel (256x256/BK=64, 4-phase counted-vmcnt, LDS XOR
// swizzle, setprio). MLP/cmp GEMMs won (cmp1 100->76), batched shapes lost.
// R18: regime routing (gemm256 only for M=32768 GEMMs). 645.
// R19: attn_kernel fused score+bias+softmax. 682 - 6x B-panel over-fetch.
// R20: XCD-affine batch mapping in attn (8 q-blocks of a batch on ONE XCD,
// B-panel fetched once per L2). 622. attn ~48us each.
// R21: attnpv full fusion FAILED (674): PV phase is LDS-issue-bound -
// 32 ds_read_u16 + 2 conflicted b128 per 8 mfma = 220cy LDS vs 64cy MFMA;
// 13.4M bank-conflict cycles, 147us/dispatch. Old NB gemm has the same
// ratio but hides it with 4 blocks/CU overlap. Transposed-V staging moves
// the u16 cost write-side (net zero); tr_b16 reads too risky headless.
// R22: revert attention to R20 exactly; route cmp2 through gemm256 with a
// new csum epilogue (shfl_xor(16/32) k-group fold + 1 atomicAdd/col/wave).

typedef __bf16 bf16x8 __attribute__((ext_vector_type(8)));
typedef float floatx16 __attribute__((ext_vector_type(16)));
typedef float floatx4 __attribute__((ext_vector_type(4)));

__device__ __forceinline__ unsigned short f32_to_bf16(float f) {
    unsigned int u = __float_as_uint(f);
    unsigned int r = (u + 0x7FFFu + ((u >> 16) & 1u)) >> 16;
    return (unsigned short)r;
}
__device__ __forceinline__ float bf16_to_f32(unsigned short h) {
    return __uint_as_float(((unsigned int)h) << 16);
}

// async global->LDS, 16B per lane (wave-uniform base + lane*16, m104).
__device__ __forceinline__ void gload16(const void* g, void* l) {
    __builtin_amdgcn_global_load_lds(
        (const __attribute__((address_space(1))) unsigned int*)g,
        (__attribute__((address_space(3))) unsigned int*)l, 16, 0, 0);
}

#define FENCE_BAR() do { asm volatile("" ::: "memory"); \
    __builtin_amdgcn_s_barrier(); \
    asm volatile("" ::: "memory"); } while (0)

// ------------------------------------------- all weight transposes, one dispatch
struct TW {
    const float* src[8];
    unsigned short* dst[8];
    int K[8];
};
__global__ __launch_bounds__(256) void transpose_all_kernel(TW tw) {
    const int z = blockIdx.z;
    const int K = tw.K[z];
    const int k0 = blockIdx.y * 32;
    if (k0 >= K) return;
    const float* W = tw.src[z];
    unsigned short* Wt = tw.dst[z];
    __shared__ unsigned short tile[32][33];
    int n0 = blockIdx.x * 32;
    int tx = threadIdx.x & 31, ty = threadIdx.x >> 5;  // 32 x 8
    #pragma unroll
    for (int i = 0; i < 4; ++i) {
        int ky = ty + i * 8;
        tile[ky][tx] = f32_to_bf16(W[(long long)(k0 + ky) * 512 + n0 + tx]);
    }
    __syncthreads();
    #pragma unroll
    for (int i = 0; i < 4; ++i) {
        int ny = ty + i * 8;
        Wt[(long long)(n0 + ny) * K + k0 + tx] = tile[tx][ny];
    }
}

// ---------------------------------------------------------------- MFMA GEMM
// (old 128x128 2-barrier kernel - 4 blocks/CU; AF32 / NB / csum paths,
// and batched shapes where inter-block overlap beats the pipeline)
template <bool BT, bool AF32>
__global__ __launch_bounds__(256, 4) void gemm_kernel(
    const void* __restrict__ Av, const void* __restrict__ A2v, int lda, long long strideA,
    const unsigned short* __restrict__ Bw, int ldb, long long strideB, int bxor,
    const unsigned short* __restrict__ B2, const float* __restrict__ bias2, int Msplit,
    float* __restrict__ C32, unsigned short* __restrict__ Cb, int ldc, long long strideC,
    const float* __restrict__ bias, int relu, int M, int N, int K,
    float* __restrict__ csum, int swz) {
    constexpr int BBYTES = BT ? 8192 : (32 * 264);  // NB: 8448
    constexpr int BUF = 8192 + BBYTES;
    __shared__ alignas(16) char smem[2 * BUF];

    const int t = threadIdx.x;
    const int lane = t & 63;
    const int wave = t >> 6;
    const int wm = (wave >> 1) * 64;
    const int wn = (wave & 1) * 64;
    const int ln = lane & 31;   // m/n within 32-subtile
    const int h = lane >> 5;    // k-half

    int bx = blockIdx.x, by = blockIdx.y, bz = blockIdx.z;
    if (swz == 1) {             // batch-1: same-A groups per XCD
        int Nt = gridDim.x, Mt = gridDim.y;
        int L = by * Nt + bx;
        int x = L & 7, s = L >> 3;
        by = x * (Mt >> 3) + s / Nt;
        bx = s % Nt;
    } else if (swz == 2) {      // batched: same-(bz,by) n-blocks per XCD
        int Nt = gridDim.x, Mt = gridDim.y;
        int L = (bz * Mt + by) * Nt + bx;
        int x = L & 7, s = L >> 3;
        int mg = x * ((Mt * (int)gridDim.z) >> 3) + s / Nt;
        bx = s % Nt;
        by = mg % Mt;
        bz = mg / Mt;
    }
    const int m0 = by * 128;
    const int n0 = bx * 128;
    const int bzB = (bz + bxor) & ((int)gridDim.z - 1);

    // per-row operand switch (merged projection)
    const unsigned short* B = Bw;
    const float* biasp = bias;
    long long mA = m0;
    if (Msplit && m0 >= Msplit) {
        if (B2) B = B2;
        if (bias2) biasp = bias2;
        if (A2v) { Av = A2v; mA = m0 - Msplit; }
    }

    const float* aptrF = nullptr;
    const unsigned short* aptrH = nullptr;
    if constexpr (AF32)
        aptrF = (const float*)Av + (long long)bz * strideA +
                (mA + (t >> 1)) * (long long)lda + (t & 1) * 16;
    else
        aptrH = (const unsigned short*)Av + (long long)bz * strideA +
                (mA + (t >> 1)) * (long long)lda + (t & 1) * 16;
    const unsigned short* bptr;
    if (BT)
        bptr = B + (long long)bzB * strideB +
               (long long)(n0 + (t >> 1)) * ldb + (t & 1) * 16;
    else
        bptr = B + (long long)bzB * strideB +
               (long long)(t >> 4) * ldb + n0 + (t & 15) * 8;
    const long long bstep = BT ? 8 : 16 * (long long)ldb;

    const int aoff = ((t & 1) * 256 + (t >> 1)) * 16;
    const int boff = BT ? (8192 + ((t & 1) * 256 + (t >> 1)) * 16)
                        : (8192 + (t >> 4) * 264 + (t & 15) * 16);
    const int boff2 = BT ? 2048 : 16 * 264;

    floatx16 acc[2][2];
    #pragma unroll
    for (int im = 0; im < 2; ++im)
        #pragma unroll
        for (int in = 0; in < 2; ++in)
            acc[im][in] = (floatx16)(0.f);

    uint4 va0, va1, vb0, vb1;
    float4 fa0, fa1, fa2, fa3;

    auto loadA = [&]() {
        if constexpr (AF32) {
            fa0 = *(const float4*)(aptrF);
            fa1 = *(const float4*)(aptrF + 4);
            fa2 = *(const float4*)(aptrF + 8);
            fa3 = *(const float4*)(aptrF + 12);
            aptrF += 32;
        } else {
            va0 = *(const uint4*)(aptrH);
            va1 = *(const uint4*)(aptrH + 8);
            aptrH += 32;
        }
    };
    auto loadB = [&]() {
        vb0 = *(const uint4*)(bptr);
        vb1 = *(const uint4*)(bptr + bstep);
        bptr += BT ? 32 : 32 * (long long)ldb;
    };
    auto commit = [&](char* buf) {
        if constexpr (AF32) {
            union { uint4 q; unsigned short u[8]; } c0, c1;
            c0.u[0] = f32_to_bf16(fa0.x); c0.u[1] = f32_to_bf16(fa0.y);
            c0.u[2] = f32_to_bf16(fa0.z); c0.u[3] = f32_to_bf16(fa0.w);
            c0.u[4] = f32_to_bf16(fa1.x); c0.u[5] = f32_to_bf16(fa1.y);
            c0.u[6] = f32_to_bf16(fa1.z); c0.u[7] = f32_to_bf16(fa1.w);
            c1.u[0] = f32_to_bf16(fa2.x); c1.u[1] = f32_to_bf16(fa2.y);
            c1.u[2] = f32_to_bf16(fa2.z); c1.u[3] = f32_to_bf16(fa2.w);
            c1.u[4] = f32_to_bf16(fa3.x); c1.u[5] = f32_to_bf16(fa3.y);
            c1.u[6] = f32_to_bf16(fa3.z); c1.u[7] = f32_to_bf16(fa3.w);
            *(uint4*)(buf + aoff) = c0.q;
            *(uint4*)(buf + aoff + 2048) = c1.q;
        } else {
            *(uint4*)(buf + aoff) = va0;
            *(uint4*)(buf + aoff + 2048) = va1;
        }
        *(uint4*)(buf + boff) = vb0;
        *(uint4*)(buf + boff + boff2) = vb1;
    };

    loadA(); loadB();
    commit(smem);
    loadA(); loadB();
    __syncthreads();

    int p = 0;
    for (int k0 = 0; k0 < K; k0 += 32) {
        const char* base = smem + p * BUF;
        #pragma unroll
        for (int s = 0; s < 2; ++s) {
            bf16x8 a[2], b[2];
            #pragma unroll
            for (int im = 0; im < 2; ++im)
                a[im] = *(const bf16x8*)(base + ((s * 2 + h) * 128 + wm + im * 32 + ln) * 16);
            if (BT) {
                #pragma unroll
                for (int in = 0; in < 2; ++in)
                    b[in] = *(const bf16x8*)(base + 8192 +
                                             ((s * 2 + h) * 128 + wn + in * 32 + ln) * 16);
            } else {
                #pragma unroll
                for (int in = 0; in < 2; ++in) {
                    union { bf16x8 v; unsigned short u[8]; } u;
                    #pragma unroll
                    for (int j = 0; j < 8; ++j)
                        u.u[j] = *(const unsigned short*)(base + 8192 +
                                 (s * 16 + h * 8 + j) * 264 + (wn + in * 32 + ln) * 2);
                    b[in] = u.v;
                }
            }
            #pragma unroll
            for (int im = 0; im < 2; ++im)
                #pragma unroll
                for (int in = 0; in < 2; ++in)
                    acc[im][in] = __builtin_amdgcn_mfma_f32_32x32x16_bf16(
                        a[im], b[in], acc[im][in], 0, 0, 0);
        }

        if (k0 + 32 < K) {
            commit(smem + (p ^ 1) * BUF);
            if (k0 + 64 < K) { loadA(); loadB(); }
            __syncthreads();
            p ^= 1;
        }
    }

    if (csum) {
        const int bidx = m0 >> 9;
        const long long cbase = (long long)(bidx & 31) * 1024 + (bidx >> 5) * 512;
        #pragma unroll
        for (int in = 0; in < 2; ++in) {
            int n = n0 + wn + in * 32 + ln;
            float bn = biasp ? biasp[n] : 0.f;
            float s = 0.f;
            #pragma unroll
            for (int im = 0; im < 2; ++im)
                #pragma unroll
                for (int r = 0; r < 16; ++r) {
                    float v = acc[im][in][r] + bn;
                    if (relu) v = fmaxf(v, 0.f);
                    s += v;
                }
            s += __shfl_xor(s, 32);
            if (lane < 32) atomicAdd(&csum[cbase + n], s);
        }
        return;
    }

    float* C32b = C32 ? C32 + (long long)bz * strideC : nullptr;
    unsigned short* Cbb = Cb ? Cb + (long long)bz * strideC : nullptr;
    #pragma unroll
    for (int im = 0; im < 2; ++im) {
        #pragma unroll
        for (int in = 0; in < 2; ++in) {
            int n = n0 + wn + in * 32 + ln;
            float bn = biasp ? biasp[n] : 0.f;
            #pragma unroll
            for (int r = 0; r < 16; ++r) {
                int m = m0 + wm + im * 32 + (r & 3) + 8 * (r >> 2) + 4 * h;
                float v = acc[im][in][r] + bn;
                if (relu) v = fmaxf(v, 0.f);
                long long off = (long long)m * ldc + n;
                if (C32b) C32b[off] = v;
                if (Cbb) Cbb[off] = f32_to_bf16(v);
            }
        }
    }
}

// --------------------------------------------------- 256x256 8-phase GEMM
// (see R17 header; used for the M=32768 weight GEMMs. R22: + csum epilogue
// for cmp2 - per-column relu-sum, shfl_xor(16/32) folds the 4 k-group
// lanes, one atomicAdd per column per wave.)
__global__ __launch_bounds__(512, 2) void gemm256_kernel(
    const unsigned short* __restrict__ Aw, int lda, long long strideA,
    const unsigned short* __restrict__ Bw, int ldb, long long strideB, int bxor,
    float* __restrict__ C32, unsigned short* __restrict__ Cb, int ldc, long long strideC,
    const float* __restrict__ bias, int relu, int K,
    float* __restrict__ csum) {
    extern __shared__ __align__(16) char smem[];

    const int tid = threadIdx.x;
    const int lane = tid & 63;
    const int wave = tid >> 6;
    const int wr = wave >> 2;           // 0..1 -> 128-row half
    const int wc = wave & 3;            // 0..3 -> 64-col quarter

    int bx = blockIdx.x, by = blockIdx.y, bz = blockIdx.z;
    {
        const int gx = gridDim.x, gy = gridDim.y;
        const int nwg = gx * gy * (int)gridDim.z;
        if ((nwg & 7) == 0) {
            int L = (bz * gy + by) * gx + bx;
            int flat = (L & 7) * (nwg >> 3) + (L >> 3);
            bx = flat % gx;
            int R = flat / gx;
            by = R % gy;
            bz = R / gy;
        }
    }
    const int m0 = by * 256;
    const int n0 = bx * 256;
    const int bzB = (bz + bxor) & ((int)gridDim.z - 1);

    const int rowT = tid >> 3;                       // 0..63
    const int chS = (tid & 7) ^ (rowT & 7);
    const long long ldaB = (long long)lda * 2;
    const long long ldbB = (long long)ldb * 2;
    const char* aG = (const char*)Aw +
        ((long long)bz * strideA + (long long)(m0 + rowT) * lda) * 2 + chS * 16;
    const char* bG = (const char*)Bw +
        ((long long)bzB * strideB + (long long)(n0 + rowT) * ldb) * 2 + chS * 16;
    const int dOff = tid * 16;

    auto stA = [&](int tt, int h) {                  // stage A half-tile h of K-tile tt
        const char* g = aG + (long long)(h * 128) * ldaB + (long long)tt * 128;
        char* l = smem + (tt & 1) * 65536 + h * 16384 + dOff;
        gload16(g, l);
        gload16(g + 64 * ldaB, l + 8192);
    };
    auto stB = [&](int tt, int h) {
        const char* g = bG + (long long)(h * 128) * ldbB + (long long)tt * 128;
        char* l = smem + (tt & 1) * 65536 + 32768 + h * 16384 + dOff;
        gload16(g, l);
        gload16(g + 64 * ldbB, l + 8192);
    };

    const int l15 = lane & 15;
    const int lk = lane >> 4;                        // k-group 0..3
    const int swzb = (lane & 7) << 4;
    const int c0 = (lk * 16) ^ swzb;                 // kk=0 col bytes
    const int c1 = (64 + lk * 16) ^ swzb;            // kk=1
    const int arow = (wr * 128 + l15) * 128;
    const int brow = 32768 + (wc * 64 + l15) * 128;

    floatx4 acc[8][4];
    #pragma unroll
    for (int mf = 0; mf < 8; ++mf)
        #pragma unroll
        for (int nf = 0; nf < 4; ++nf)
            acc[mf][nf] = (floatx4)(0.f);

    const int NT = K >> 6;

    stA(0, 0); stA(0, 1); stB(0, 0); stB(0, 1);
    if (NT > 1) {
        stB(1, 0); stB(1, 1);
        asm volatile("s_waitcnt vmcnt(4)" ::: "memory");
    } else {
        asm volatile("s_waitcnt vmcnt(0)" ::: "memory");
    }
    FENCE_BAR();

    bf16x8 a[4][2], b[4][2];
    for (int t = 0; t < NT; ++t) {
        const char* buf = smem + (t & 1) * 65536;
        const char* aB = buf + arow;
        const char* bB = buf + brow;

        // ---- P0: A mf0-3 + B nf0-1; stage A(t+1) h0
        #pragma unroll
        for (int mf = 0; mf < 4; ++mf) {
            a[mf][0] = *(const bf16x8*)(aB + mf * 2048 + c0);
            a[mf][1] = *(const bf16x8*)(aB + mf * 2048 + c1);
        }
        #pragma unroll
        for (int nf = 0; nf < 2; ++nf) {
            b[nf][0] = *(const bf16x8*)(bB + nf * 2048 + c0);
            b[nf][1] = *(const bf16x8*)(bB + nf * 2048 + c1);
        }
        if (t + 1 < NT) stA(t + 1, 0);
        FENCE_BAR();
        __builtin_amdgcn_s_setprio(1);
        #pragma unroll
        for (int mf = 0; mf < 4; ++mf)
            #pragma unroll
            for (int nf = 0; nf < 2; ++nf) {
                acc[mf][nf] = __builtin_amdgcn_mfma_f32_16x16x32_bf16(
                    a[mf][0], b[nf][0], acc[mf][nf], 0, 0, 0);
                acc[mf][nf] = __builtin_amdgcn_mfma_f32_16x16x32_bf16(
                    a[mf][1], b[nf][1], acc[mf][nf], 0, 0, 0);
            }
        __builtin_amdgcn_s_setprio(0);
        FENCE_BAR();

        // ---- P1: B nf2-3; stage A(t+1) h1
        #pragma unroll
        for (int nf = 2; nf < 4; ++nf) {
            b[nf][0] = *(const bf16x8*)(bB + nf * 2048 + c0);
            b[nf][1] = *(const bf16x8*)(bB + nf * 2048 + c1);
        }
        if (t + 1 < NT) stA(t + 1, 1);
        FENCE_BAR();
        __builtin_amdgcn_s_setprio(1);
        #pragma unroll
        for (int mf = 0; mf < 4; ++mf)
            #pragma unroll
            for (int nf = 2; nf < 4; ++nf) {
                acc[mf][nf] = __builtin_amdgcn_mfma_f32_16x16x32_bf16(
                    a[mf][0], b[nf][0], acc[mf][nf], 0, 0, 0);
                acc[mf][nf] = __builtin_amdgcn_mfma_f32_16x16x32_bf16(
                    a[mf][1], b[nf][1], acc[mf][nf], 0, 0, 0);
            }
        __builtin_amdgcn_s_setprio(0);
        FENCE_BAR();

        // ---- P2: A mf4-7; stage B(t+2) h0
        #pragma unroll
        for (int mf = 0; mf < 4; ++mf) {
            a[mf][0] = *(const bf16x8*)(aB + (4 + mf) * 2048 + c0);
            a[mf][1] = *(const bf16x8*)(aB + (4 + mf) * 2048 + c1);
        }
        if (t + 2 < NT) stB(t + 2, 0);
        FENCE_BAR();
        __builtin_amdgcn_s_setprio(1);
        #pragma unroll
        for (int mf = 0; mf < 4; ++mf)
            #pragma unroll
            for (int nf = 2; nf < 4; ++nf) {
                acc[4 + mf][nf] = __builtin_amdgcn_mfma_f32_16x16x32_bf16(
                    a[mf][0], b[nf][0], acc[4 + mf][nf], 0, 0, 0);
                acc[4 + mf][nf] = __builtin_amdgcn_mfma_f32_16x16x32_bf16(
                    a[mf][1], b[nf][1], acc[4 + mf][nf], 0, 0, 0);
            }
        __builtin_amdgcn_s_setprio(0);
        FENCE_BAR();

        // ---- P3: stage B(t+2) h1; counted vmcnt => tile t+1 landed
        if (t + 2 < NT) {
            stB(t + 2, 1);
            asm volatile("s_waitcnt vmcnt(4)" ::: "memory");
        } else {
            asm volatile("s_waitcnt vmcnt(0)" ::: "memory");
        }
        FENCE_BAR();
        __builtin_amdgcn_s_setprio(1);
        #pragma unroll
        for (int mf = 0; mf < 4; ++mf)
            #pragma unroll
            for (int nf = 0; nf < 2; ++nf) {
                acc[4 + mf][nf] = __builtin_amdgcn_mfma_f32_16x16x32_bf16(
                    a[mf][0], b[nf][0], acc[4 + mf][nf], 0, 0, 0);
                acc[4 + mf][nf] = __builtin_amdgcn_mfma_f32_16x16x32_bf16(
                    a[mf][1], b[nf][1], acc[4 + mf][nf], 0, 0, 0);
            }
        __builtin_amdgcn_s_setprio(0);
        FENCE_BAR();
    }

    // ---- csum epilogue (cmp2): column sums of relu(acc+bias) into agg
    if (csum) {
        const int bidx = m0 >> 9;
        const long long cbase = (long long)(bidx & 31) * 1024 + (bidx >> 5) * 512;
        #pragma unroll
        for (int nf = 0; nf < 4; ++nf) {
            const int n = n0 + wc * 64 + nf * 16 + l15;
            const float bn = bias ? bias[n] : 0.f;
            float s = 0.f;
            #pragma unroll
            for (int mf = 0; mf < 8; ++mf)
                #pragma unroll
                for (int r = 0; r < 4; ++r) {
                    float v = acc[mf][nf][r] + bn;
                    if (relu) v = fmaxf(v, 0.f);
                    s += v;
                }
            s += __shfl_xor(s, 16);
            s += __shfl_xor(s, 32);
            if (lk == 0) atomicAdd(&csum[cbase + n], s);
        }
        return;
    }

    // ---- epilogue: C/D map col=lane&15, row=(lane>>4)*4+r (m89)
    const int rg = (lane >> 4) * 4;
    float* C32b = C32 ? C32 + (long long)bz * strideC : nullptr;
    unsigned short* Cbb = Cb ? Cb + (long long)bz * strideC : nullptr;
    #pragma unroll
    for (int nf = 0; nf < 4; ++nf) {
        const int n = n0 + wc * 64 + nf * 16 + l15;
        const float bn = bias ? bias[n] : 0.f;
        #pragma unroll
        for (int mf = 0; mf < 8; ++mf) {
            #pragma unroll
            for (int r = 0; r < 4; ++r) {
                int m = m0 + wr * 128 + mf * 16 + rg + r;
                float v = acc[mf][nf][r] + bn;
                if (relu) v = fmaxf(v, 0.f);
                long long off = (long long)m * ldc + n;
                if (C32b) C32b[off] = v;
                if (Cbb) Cbb[off] = f32_to_bf16(v);
            }
        }
    }
}

// --------------------------------------- fused score + rel-bias + softmax
// One block: 64 query rows x all 512 keys x 1 batch. 4 waves = 128-col
// quarters; per wave acc[2 msub][4 nsub] of 32x32 (floatx16).
// R20: XCD-affine mapping - all 8 query-blocks of one batch on ONE XCD,
// consecutive in dispatch, so the shared 0.5MB B-panel is fetched once
// into that XCD's L2 (8 concurrent batches/XCD = 4MB = L2 capacity).
__global__ __launch_bounds__(256, 2) void attn_kernel(
    const unsigned short* __restrict__ F,   // [64][512][512] bf16
    int bxor,
    unsigned short* __restrict__ att,       // [64][512][1024] bf16 rows
    const float* __restrict__ de, int rel) {
    constexpr int BUF = 36864;               // 4096 (A) + 32768 (B)
    __shared__ alignas(16) char smem[2 * BUF];
    __shared__ alignas(16) float red[2][64][4];
    __shared__ float deL[23];

    const int t = threadIdx.x;
    const int lane = t & 63;
    const int wave = t >> 6;                 // n-quarter 0..3
    const int ln = lane & 31;
    const int h = lane >> 5;

    // XCD-affine remap (R20)
    const int orig = blockIdx.y * (int)gridDim.x + blockIdx.x;
    const int xcd = orig & 7;
    const int s8 = orig >> 3;
    const int by = s8 & 7;                   // query block 0..7
    const int bz = xcd + ((s8 >> 3) << 3);   // batch 0..63
    const int m0 = by * 64;
    const int bzB = (bz + bxor) & 63;

    if (t < 23) deL[t] = de[t];

    // staging: A row t>>2 (64 rows), k-plane t&3 (8 elems each);
    // B row t>>1 (+128j), k-chunk t&1 (16 elems = planes 2c,2c+1).
    const unsigned short* aptr = F + (long long)bz * (512 * 512) +
                                 (m0 + (t >> 2)) * 512 + (t & 3) * 8;
    const unsigned short* bptr = F + (long long)bzB * (512 * 512) +
                                 (t >> 1) * 512 + (t & 1) * 16;
    const int aoff = ((t & 3) * 64 + (t >> 2)) * 16;
    const int c2 = (t & 1) * 2;
    const int brow = (t >> 1) * 16;

    floatx16 acc[2][4];
    #pragma unroll
    for (int mf = 0; mf < 2; ++mf)
        #pragma unroll
        for (int nf = 0; nf < 4; ++nf)
            acc[mf][nf] = (floatx16)(0.f);

    uint4 qa, q0a, q0b, q1a, q1b, q2a, q2b, q3a, q3b;   // named scalars (R12)
    auto load = [&]() {
        qa  = *(const uint4*)(aptr);
        q0a = *(const uint4*)(bptr);
        q0b = *(const uint4*)(bptr + 8);
        q1a = *(const uint4*)(bptr + 65536);
        q1b = *(const uint4*)(bptr + 65536 + 8);
        q2a = *(const uint4*)(bptr + 131072);
        q2b = *(const uint4*)(bptr + 131072 + 8);
        q3a = *(const uint4*)(bptr + 196608);
        q3b = *(const uint4*)(bptr + 196608 + 8);
        aptr += 32; bptr += 32;
    };
    auto commit = [&](char* buf) {
        *(uint4*)(buf + aoff) = qa;
        char* bb = buf + 4096;
        *(uint4*)(bb + (c2 + 0) * 8192 + brow) = q0a;
        *(uint4*)(bb + (c2 + 1) * 8192 + brow) = q0b;
        *(uint4*)(bb + (c2 + 0) * 8192 + brow + 128 * 16) = q1a;
        *(uint4*)(bb + (c2 + 1) * 8192 + brow + 128 * 16) = q1b;
        *(uint4*)(bb + (c2 + 0) * 8192 + brow + 256 * 16) = q2a;
        *(uint4*)(bb + (c2 + 1) * 8192 + brow + 256 * 16) = q2b;
        *(uint4*)(bb + (c2 + 0) * 8192 + brow + 384 * 16) = q3a;
        *(uint4*)(bb + (c2 + 1) * 8192 + brow + 384 * 16) = q3b;
    };

    load(); commit(smem); load();
    __syncthreads();

    int p = 0;
    for (int k0 = 0; k0 < 512; k0 += 32) {
        const char* buf = smem + p * BUF;
        #pragma unroll
        for (int s = 0; s < 2; ++s) {
            bf16x8 a[2], b[4];
            #pragma unroll
            for (int mf = 0; mf < 2; ++mf)
                a[mf] = *(const bf16x8*)(buf + ((s * 2 + h) * 64 + mf * 32 + ln) * 16);
            #pragma unroll
            for (int nf = 0; nf < 4; ++nf)
                b[nf] = *(const bf16x8*)(buf + 4096 + (s * 2 + h) * 8192 +
                                         (wave * 128 + nf * 32 + ln) * 16);
            #pragma unroll
            for (int mf = 0; mf < 2; ++mf)
                #pragma unroll
                for (int nf = 0; nf < 4; ++nf)
                    acc[mf][nf] = __builtin_amdgcn_mfma_f32_32x32x16_bf16(
                        a[mf], b[nf], acc[mf][nf], 0, 0, 0);
        }
        if (k0 + 32 < 512) {
            commit(smem + (p ^ 1) * BUF);
            if (k0 + 64 < 512) load();
            __syncthreads();
            p ^= 1;
        }
    }

    // ---- rel-distance bias (self-attention only)
    if (rel) {
        #pragma unroll
        for (int mf = 0; mf < 2; ++mf)
            #pragma unroll
            for (int nf = 0; nf < 4; ++nf)
                #pragma unroll
                for (int r = 0; r < 16; ++r) {
                    int row = m0 + mf * 32 + (r & 3) + 8 * (r >> 2) + 4 * h;
                    int col = wave * 128 + nf * 32 + ln;
                    int d = min(11, max(-11, col - row));
                    acc[mf][nf][r] += deL[d + 11];
                }
    }

    // ---- row max: in-lane (4 nsub) -> shfl over 32-lane half -> LDS x-wave
    #pragma unroll
    for (int mf = 0; mf < 2; ++mf)
        #pragma unroll
        for (int r = 0; r < 16; ++r) {
            float mx = fmaxf(fmaxf(acc[mf][0][r], acc[mf][1][r]),
                             fmaxf(acc[mf][2][r], acc[mf][3][r]));
            #pragma unroll
            for (int o = 16; o > 0; o >>= 1) mx = fmaxf(mx, __shfl_xor(mx, o));
            if (ln == 0)
                red[0][mf * 32 + (r & 3) + 8 * (r >> 2) + 4 * h][wave] = mx;
        }
    __syncthreads();

    // ---- exp + row sum
    #pragma unroll
    for (int mf = 0; mf < 2; ++mf)
        #pragma unroll
        for (int r = 0; r < 16; ++r) {
            const int rl = mf * 32 + (r & 3) + 8 * (r >> 2) + 4 * h;
            float4 q = *(const float4*)red[0][rl];
            float mx = fmaxf(fmaxf(q.x, q.y), fmaxf(q.z, q.w));
            float s = 0.f;
            #pragma unroll
            for (int nf = 0; nf < 4; ++nf) {
                acc[mf][nf][r] = __expf(acc[mf][nf][r] - mx);
                s += acc[mf][nf][r];
            }
            #pragma unroll
            for (int o = 16; o > 0; o >>= 1) s += __shfl_xor(s, o);
            if (ln == 0) red[1][rl][wave] = s;
        }
    __syncthreads();

    // ---- normalize + bf16 write (att rows have lda 1024)
    unsigned short* ab = att + ((long long)bz * 512 + m0) * 1024;
    #pragma unroll
    for (int mf = 0; mf < 2; ++mf)
        #pragma unroll
        for (int r = 0; r < 16; ++r) {
            const int rl = mf * 32 + (r & 3) + 8 * (r >> 2) + 4 * h;
            float4 q = *(const float4*)red[1][rl];
            float inv = 1.f / (q.x + q.y + q.z + q.w);
            #pragma unroll
            for (int nf = 0; nf < 4; ++nf) {
                int col = wave * 128 + nf * 32 + ln;
                ab[(long long)rl * 1024 + col] = f32_to_bf16(acc[mf][nf][r] * inv);
            }
        }
}

// ------------------------------------------- aggregate MLP layer (fp32)
__global__ __launch_bounds__(512) void mlp_agg_kernel(const float* __restrict__ X,
                                                      const float* __restrict__ W,
                                                      const float* __restrict__ bias,
                                                      float* __restrict__ out,
                                                      int K, int N, int relu) {
    const int b = blockIdx.y;
    const int nl = threadIdx.x & 63;
    const int n = blockIdx.x * 64 + nl;
    const int ks = threadIdx.x >> 6;          // 0..7
    const int kchunk = K >> 3;
    const float* Xb = X + (long long)b * K;
    const int k0 = ks * kchunk;
    float s = 0.f;
    #pragma unroll 8
    for (int k = k0; k < k0 + kchunk; ++k)
        s += Xb[k] * W[(long long)k * N + n];
    __shared__ float red[8][64];
    red[ks][nl] = s;
    __syncthreads();
    if (threadIdx.x < 64) {
        float t = 0.f;
        #pragma unroll
        for (int i = 0; i < 8; ++i) t += red[i][threadIdx.x];
        t += bias[n];
        if (relu) t = fmaxf(t, 0.f);
        out[(long long)b * N + n] = t;
    }
}

// ---------------------------------------------------------------- host side
static void gemm(hipStream_t st, bool bt, bool af32,
                 const void* A, const void* A2, int lda, long long sA,
                 const void* B, int ldb, long long sB, int bxor,
                 const void* B2, const float* bias2, int Msplit,
                 float* C32, void* Cb, int ldc, long long sC,
                 const float* bias, int relu, int M, int N, int K, int batch,
                 float* csum = nullptr) {
    dim3 g(N / 128, M / 128, batch), blk(256);
    int swz = 0;
    if (batch == 1 && (M / 128) % 8 == 0) swz = 1;
    else if (batch > 1 && ((M / 128) * batch) % 8 == 0) swz = 2;
    if (bt) {
        if (af32)
            gemm_kernel<true, true><<<g, blk, 0, st>>>(
                A, A2, lda, sA, (const unsigned short*)B, ldb, sB, bxor,
                (const unsigned short*)B2, bias2, Msplit,
                C32, (unsigned short*)Cb, ldc, sC, bias, relu, M, N, K, csum, swz);
        else
            gemm_kernel<true, false><<<g, blk, 0, st>>>(
                A, A2, lda, sA, (const unsigned short*)B, ldb, sB, bxor,
                (const unsigned short*)B2, bias2, Msplit,
                C32, (unsigned short*)Cb, ldc, sC, bias, relu, M, N, K, csum, swz);
    } else {
        gemm_kernel<false, false><<<g, blk, 0, st>>>(
            A, A2, lda, sA, (const unsigned short*)B, ldb, sB, bxor,
            (const unsigned short*)B2, bias2, Msplit,
            C32, (unsigned short*)Cb, ldc, sC, bias, relu, M, N, K, csum, swz);
    }
}

static void gemm256(hipStream_t st,
                    const void* A, int lda, long long sA,
                    const void* B, int ldb, long long sB, int bxor,
                    float* C32, void* Cb, int ldc, long long sC,
                    const float* bias, int relu, int M, int N, int K, int batch,
                    float* csum = nullptr) {
    static bool inited = false;
    if (!inited) {
        hipFuncSetAttribute(reinterpret_cast<const void*>(gemm256_kernel),
                            hipFuncAttributeMaxDynamicSharedMemorySize, 131072);
        inited = true;
    }
    dim3 g(N / 256, M / 256, batch);
    gemm256_kernel<<<g, 512, 131072, st>>>(
        (const unsigned short*)A, lda, sA,
        (const unsigned short*)B, ldb, sB, bxor,
        C32, (unsigned short*)Cb, ldc, sC, bias, relu, K, csum);
}

extern "C" void kernel_launch(void* const* d_in, const int* in_sizes, int n_in,
                              void* d_out, int out_size, void* d_ws, size_t ws_size,
                              hipStream_t stream) {
    const int B = 32, SEQ = 512;
    const int MT = B * SEQ;      // 16384 rows per side
    const int M2 = 2 * MT;       // 32768 merged rows

    const float* prem = (const float*)d_in[0];
    const float* hypo = (const float*)d_in[1];
    const float* Wpx = (const float*)d_in[4];  const float* bpx = (const float*)d_in[5];
    const float* Wpy = (const float*)d_in[6];  const float* bpy = (const float*)d_in[7];
    const float* de  = (const float*)d_in[8];
    const float* Ws1 = (const float*)d_in[9];  const float* bs1 = (const float*)d_in[10];
    const float* Ws2 = (const float*)d_in[11]; const float* bs2 = (const float*)d_in[12];
    const float* Wa1 = (const float*)d_in[13]; const float* ba1 = (const float*)d_in[14];
    const float* Wa2 = (const float*)d_in[15]; const float* ba2 = (const float*)d_in[16];
    const float* Wc1 = (const float*)d_in[17]; const float* bc1 = (const float*)d_in[18];
    const float* Wc2 = (const float*)d_in[19]; const float* bc2 = (const float*)d_in[20];
    const float* Wg1 = (const float*)d_in[21]; const float* bg1 = (const float*)d_in[22];
    const float* Wg2 = (const float*)d_in[23]; const float* bg2 = (const float*)d_in[24];

    // ---- workspace carve (bytes, 256-aligned). Adjacency REQUIRED:
    // prem_bf|hypo_bf contiguous, premcat|hypocat contiguous. scores fp32
    // [64][512][512]; h1/att alias it with disjoint lifetimes.
    char* p = (char*)d_ws;
    auto alloc = [&](size_t bytes) { char* r = p; p += (bytes + 255) & ~(size_t)255; return r; };
    unsigned short* prem_bf = (unsigned short*)alloc((size_t)MT * 512 * 2);
    unsigned short* hypo_bf = (unsigned short*)alloc((size_t)MT * 512 * 2);
    unsigned short* premcat = (unsigned short*)alloc((size_t)MT * 2048 * 2);
    unsigned short* hypocat = (unsigned short*)alloc((size_t)MT * 2048 * 2);
    float* scores = (float*)alloc((size_t)64 * SEQ * SEQ * 4);                  // 64 MB
    unsigned short* h1 = (unsigned short*)scores;                               // alias
    unsigned short* att = (unsigned short*)scores;                              // alias, lda 1024
    unsigned short* Wpx_t = (unsigned short*)alloc(512 * 512 * 2);
    unsigned short* Wpy_t = (unsigned short*)alloc(512 * 512 * 2);
    unsigned short* Ws1_t = (unsigned short*)alloc(512 * 512 * 2);
    unsigned short* Ws2_t = (unsigned short*)alloc(512 * 512 * 2);
    unsigned short* Wa1_t = (unsigned short*)alloc(512 * 1024 * 2);
    unsigned short* Wa2_t = (unsigned short*)alloc(512 * 512 * 2);
    unsigned short* Wc1_t = (unsigned short*)alloc(512 * 2048 * 2);
    unsigned short* Wc2_t = (unsigned short*)alloc(512 * 512 * 2);
    float* agg  = (float*)alloc(32 * 1024 * 4);
    float* aggh = (float*)alloc(32 * 512 * 4);
    (void)hypo_bf; (void)hypocat; (void)scores;

    const long long sAtt = (long long)SEQ * 1024;     // att batch stride (lda 1024)
    const long long sCat = (long long)SEQ * 2048;     // cat batch stride

    // ---- setup: all 8 weight transposes in ONE dispatch; zero agg
    {
        TW tw;
        tw.src[0] = Wpy; tw.dst[0] = Wpy_t; tw.K[0] = 512;
        tw.src[1] = Wpx; tw.dst[1] = Wpx_t; tw.K[1] = 512;
        tw.src[2] = Ws1; tw.dst[2] = Ws1_t; tw.K[2] = 512;
        tw.src[3] = Ws2; tw.dst[3] = Ws2_t; tw.K[3] = 512;
        tw.src[4] = Wa1; tw.dst[4] = Wa1_t; tw.K[4] = 1024;
        tw.src[5] = Wa2; tw.dst[5] = Wa2_t; tw.K[5] = 512;
        tw.src[6] = Wc1; tw.dst[6] = Wc1_t; tw.K[6] = 2048;
        tw.src[7] = Wc2; tw.dst[7] = Wc2_t; tw.K[7] = 512;
        transpose_all_kernel<<<dim3(16, 64, 8), 256, 0, stream>>>(tw);
        hipMemsetAsync(agg, 0, 32 * 1024 * sizeof(float), stream);
    }

    // ---- merged projection (fp32 A, per-row switch) - old kernel
    gemm(stream, true, true, prem, hypo, 512, 0, Wpy_t, 512, 0, 0,
         Wpx_t, bpx, MT, nullptr, premcat, 2048, 0, bpy, 0, M2, 512, 512, 1);

    // ---- self-attention MLP, merged: f = mlp2(cat[:, :512])  [gemm256]
    gemm256(stream, premcat, 2048, 0, Ws1_t, 512, 0, 0,
            nullptr, h1, 512, 0, bs1, 1, M2, 512, 512, 1);
    gemm256(stream, h1, 512, 0, Ws2_t, 512, 0, 0,
            nullptr, prem_bf, 512, 0, bs2, 1, M2, 512, 512, 1);

    // ---- self attention, batch 64: fused score+bias+softmax -> att (bf16)
    attn_kernel<<<dim3(8, 64), 256, 0, stream>>>(prem_bf, 0, att, de, 1);
    gemm(stream, false, false, att, nullptr, 1024, sAtt, premcat, 2048, sCat, 0,
         nullptr, nullptr, 0, nullptr, premcat + 512, 2048, sCat, nullptr, 0, 512, 512, 512, 64);

    // ---- cross-attention MLP, merged: g = mlp2(cat[:, :1024])  [gemm256]
    gemm256(stream, premcat, 2048, 0, Wa1_t, 1024, 0, 0,
            nullptr, h1, 512, 0, ba1, 1, M2, 512, 1024, 1);
    gemm256(stream, h1, 512, 0, Wa2_t, 512, 0, 0,
            nullptr, prem_bf, 512, 0, ba2, 1, M2, 512, 512, 1);

    // ---- cross attention, batch 64 with B-batch rotation (z+32)&63
    attn_kernel<<<dim3(8, 64), 256, 0, stream>>>(prem_bf, 32, att, de, 0);
    gemm(stream, false, false, att, nullptr, 1024, sAtt, premcat, 2048, sCat, 32,
         nullptr, nullptr, 0, nullptr, premcat + 1024, 2048, sCat, nullptr, 0, 512, 1024, 512, 64);

    // ---- compare, merged: cmp = mlp2(cat) ; fused column-sum into agg
    gemm256(stream, premcat, 2048, 0, Wc1_t, 2048, 0, 0,
            nullptr, h1, 512, 0, bc1, 1, M2, 512, 2048, 1);
    gemm256(stream, h1, 512, 0, Wc2_t, 512, 0, 0,
            nullptr, nullptr, 512, 0, bc2, 1, M2, 512, 512, 1, agg);

    // ---- aggregate MLP
    mlp_agg_kernel<<<dim3(8, 32), 512, 0, stream>>>(agg, Wg1, bg1, aggh, 1024, 512, 1);
    mlp_agg_kernel<<<dim3(8, 32), 512, 0, stream>>>(aggh, Wg2, bg2, (float*)d_out, 512, 512, 1);
}